// Round 12
// baseline (252.848 us; speedup 1.0000x reference)
//
#include <hip/hip_runtime.h>
#include <hip/hip_bf16.h>

#define FEAT 64

// RNE pack of two fp32 into one u32 of 2 bf16 (lo, hi)
__device__ inline uint packbf2(float lo, float hi) {
    uint ul = __float_as_uint(lo), uh = __float_as_uint(hi);
    ul += 0x7FFFu + ((ul >> 16) & 1u);
    uh += 0x7FFFu + ((uh >> 16) & 1u);
    return (ul >> 16) | (uh & 0xFFFF0000u);
}

// unpack uint4 (8 bf16) -> two float4
__device__ inline void unpack8(uint4 q, float4& va, float4& vb) {
    va.x = __uint_as_float(q.x << 16);
    va.y = __uint_as_float(q.x & 0xFFFF0000u);
    va.z = __uint_as_float(q.y << 16);
    va.w = __uint_as_float(q.y & 0xFFFF0000u);
    vb.x = __uint_as_float(q.z << 16);
    vb.y = __uint_as_float(q.z & 0xFFFF0000u);
    vb.z = __uint_as_float(q.w << 16);
    vb.w = __uint_as_float(q.w & 0xFFFF0000u);
}

// ---------------------------------------------------------------------------
// prep1: blocks [0,normBlocks): inverse norms rn, raw norms nrm, and the
// NORMALIZED bf16 mirror xhn = bf16(x * rn).  Remaining blocks: row_ptr
// build from the SORTED row_index.
// ---------------------------------------------------------------------------
__global__ void prep1_kernel(const float* __restrict__ x,
                             float* __restrict__ rn,
                             float* __restrict__ nrm,
                             uint4* __restrict__ xhn,
                             const int* __restrict__ row,
                             int* __restrict__ row_ptr,
                             int N, int E, int normBlocks) {
    if ((int)blockIdx.x < normBlocks) {
        int wid  = blockIdx.x * (blockDim.x >> 6) + (threadIdx.x >> 6);
        int lane = threadIdx.x & 63;
        int g    = lane >> 3;
        int sub  = lane & 7;
        int r    = wid * 8 + g;
        if (r >= N) return;
        const char* xB = (const char*)x;
        uint roff = ((uint)r << 8) + ((uint)sub << 4);
        float4 xa = *reinterpret_cast<const float4*>(xB + roff);
        float4 xb = *reinterpret_cast<const float4*>(xB + roff + 128);
        float q = xa.x*xa.x + xa.y*xa.y + xa.z*xa.z + xa.w*xa.w
                + xb.x*xb.x + xb.y*xb.y + xb.z*xb.z + xb.w*xb.w;
        q += __shfl_xor(q, 1);
        q += __shfl_xor(q, 2);
        q += __shfl_xor(q, 4);
        float qe  = q + 1e-8f;
        float rnr = rsqrtf(qe);
        if (sub == 0) { rn[r] = rnr; nrm[r] = qe * rnr; }   // nrm = sqrt(qe)
        uint4 p;
        p.x = packbf2(xa.x * rnr, xa.y * rnr);
        p.y = packbf2(xa.z * rnr, xa.w * rnr);
        p.z = packbf2(xb.x * rnr, xb.y * rnr);
        p.w = packbf2(xb.z * rnr, xb.w * rnr);
        xhn[r * 8 + sub] = p;
    } else {
        int e = (blockIdx.x - normBlocks) * blockDim.x + threadIdx.x;
        if (e >= E) return;
        int curr = row[e];
        if (e == 0) {
            for (int r = 0; r <= curr; ++r) row_ptr[r] = 0;
        } else {
            int prev = row[e - 1];
            for (int r = prev + 1; r <= curr; ++r) row_ptr[r] = e;
        }
        if (e == E - 1) {
            for (int r = curr + 1; r <= N; ++r) row_ptr[r] = E;
        }
    }
}

// ---------------------------------------------------------------------------
// prep2: zip[e] = { col[e], bits(nrm[col[e]]) }.  Moves the scattered 4B
// norm gathers out of the fused hot loop into a max-MLP edge-parallel pass;
// the fused kernel then gets col+nrm in ONE coalesced 8B load per lane.
// ---------------------------------------------------------------------------
__global__ void prep2_kernel(const int* __restrict__ col,
                             const float* __restrict__ nrm,
                             int2* __restrict__ zip, int E) {
    int e = blockIdx.x * blockDim.x + threadIdx.x;
    if (e >= E) return;
    int c = col[e];
    zip[e] = make_int2(c, __float_as_int(nrm[c]));
}

// ---------------------------------------------------------------------------
// FUSED attention + shift-free softmax + aggregation, DEPTH-8 pipeline.
// 8 rows per wave (one 8-lane group per row).  Two 8-edge chunk buffers
// (qA/qB): while chunk t is processed, chunk t+1's 8 gather instructions
// are in flight.  All masked/garbage paths are multiplied by e=0 against
// zero-initialized finite buffers (no NaN).
// ---------------------------------------------------------------------------
#define ISSUE8(QP, Z)                                                        \
    {                                                                        \
        int c0_=__shfl((Z).x,0,8), c1_=__shfl((Z).x,1,8);                    \
        int c2_=__shfl((Z).x,2,8), c3_=__shfl((Z).x,3,8);                    \
        int c4_=__shfl((Z).x,4,8), c5_=__shfl((Z).x,5,8);                    \
        int c6_=__shfl((Z).x,6,8), c7_=__shfl((Z).x,7,8);                    \
        QP##0 = xhn[(uint)c0_*8u+sub]; QP##1 = xhn[(uint)c1_*8u+sub];        \
        QP##2 = xhn[(uint)c2_*8u+sub]; QP##3 = xhn[(uint)c3_*8u+sub];        \
        QP##4 = xhn[(uint)c4_*8u+sub]; QP##5 = xhn[(uint)c5_*8u+sub];        \
        QP##6 = xhn[(uint)c6_*8u+sub]; QP##7 = xhn[(uint)c7_*8u+sub];        \
    }

#define PROC1(Q, Z, J, BASE)                                                 \
    {                                                                        \
        float4 va_, vb_;                                                     \
        unpack8(Q, va_, vb_);                                                \
        float d_ = xa.x*va_.x + xa.y*va_.y + xa.z*va_.z + xa.w*va_.w         \
                 + xb.x*vb_.x + xb.y*vb_.y + xb.z*vb_.z + xb.w*vb_.w;        \
        d_ += __shfl_xor(d_, 1);                                             \
        d_ += __shfl_xor(d_, 2);                                             \
        d_ += __shfl_xor(d_, 4);                                             \
        float e_ = ((BASE) + (J) < deg) ? __expf(d_) : 0.f;                  \
        float n_ = __shfl(__int_as_float((Z).y), (J), 8);                    \
        s += e_;                                                             \
        float w_ = e_ * n_;                                                  \
        aa.x += w_*va_.x; aa.y += w_*va_.y; aa.z += w_*va_.z; aa.w += w_*va_.w; \
        ab.x += w_*vb_.x; ab.y += w_*vb_.y; ab.z += w_*vb_.z; ab.w += w_*vb_.w; \
    }

#define PROC8(QP, Z, BASE)                                                   \
    PROC1(QP##0, Z, 0, BASE)  PROC1(QP##1, Z, 1, BASE)                       \
    PROC1(QP##2, Z, 2, BASE)  PROC1(QP##3, Z, 3, BASE)                       \
    PROC1(QP##4, Z, 4, BASE)  PROC1(QP##5, Z, 5, BASE)                       \
    PROC1(QP##6, Z, 6, BASE)  PROC1(QP##7, Z, 7, BASE)

__global__ void fused_kernel(const float* __restrict__ x,
                             const uint4* __restrict__ xhn,
                             const float* __restrict__ rn,
                             const float* __restrict__ beta,
                             const int* __restrict__ row_ptr,
                             const int2* __restrict__ zip,
                             float* __restrict__ out, int N) {
    int wid  = blockIdx.x * (blockDim.x >> 6) + (threadIdx.x >> 6);
    int lane = threadIdx.x & 63;
    int g    = lane >> 3;               // group = row slot (0..7)
    int sub  = lane & 7;
    int r    = wid * 8 + g;
    bool rv  = (r < N);

    int start = 0, deg = 0;
    if (rv) {
        start = row_ptr[r];
        deg   = row_ptr[r + 1] - start;
    }

    // x_r scaled by beta*rn_r:  att = dot(xr_scaled, xhn_c)
    float4 xa = make_float4(0.f, 0.f, 0.f, 0.f);
    float4 xb = make_float4(0.f, 0.f, 0.f, 0.f);
    if (rv) {
        const char* xB = (const char*)x;
        uint roff = ((uint)r << 8) + ((uint)sub << 4);
        xa = *reinterpret_cast<const float4*>(xB + roff);
        xb = *reinterpret_cast<const float4*>(xB + roff + 128);
        float brn = beta[0] * rn[r];
        xa.x *= brn; xa.y *= brn; xa.z *= brn; xa.w *= brn;
        xb.x *= brn; xb.y *= brn; xb.z *= brn; xb.w *= brn;
    }

    uint4 z4 = make_uint4(0u, 0u, 0u, 0u);
    uint4 qA0=z4,qA1=z4,qA2=z4,qA3=z4,qA4=z4,qA5=z4,qA6=z4,qA7=z4;
    uint4 qB0=z4,qB1=z4,qB2=z4,qB3=z4,qB4=z4,qB5=z4,qB6=z4,qB7=z4;

    int2 zipA = make_int2(0, 0), zipB = make_int2(0, 0);
    if (sub < deg)     zipA = zip[start + sub];
    if (8 + sub < deg) zipB = zip[start + 8 + sub];
    if (deg > 0) ISSUE8(qA, zipA);
    if (deg > 8) ISSUE8(qB, zipB);

    float  s  = 0.f;
    float4 aa = make_float4(0.f, 0.f, 0.f, 0.f);
    float4 ab = make_float4(0.f, 0.f, 0.f, 0.f);

    for (int base = 0; base < deg; base += 16) {
        // ---- half A: process chunk base (qA), refill with chunk base+16 ----
        int2 zipNA = make_int2(0, 0);
        if (base + 16 + sub < deg) zipNA = zip[start + base + 16 + sub];
        PROC8(qA, zipA, base);
        if (base + 16 < deg) ISSUE8(qA, zipNA);
        zipA = zipNA;

        // ---- half B: process chunk base+8 (qB), refill with chunk base+24 --
        int2 zipNB = make_int2(0, 0);
        if (base + 24 + sub < deg) zipNB = zip[start + base + 24 + sub];
        PROC8(qB, zipB, base + 8);
        if (base + 24 < deg) ISSUE8(qB, zipNB);
        zipB = zipNB;
    }

    float inv = 1.0f / fmaxf(s, 1e-16f);      // deg==0 -> out = 0
    if (rv) {
        uint roff = ((uint)r << 8) + ((uint)sub << 4);
        *reinterpret_cast<float4*>((char*)out + roff) =
            make_float4(aa.x * inv, aa.y * inv, aa.z * inv, aa.w * inv);
        *reinterpret_cast<float4*>((char*)out + roff + 128) =
            make_float4(ab.x * inv, ab.y * inv, ab.z * inv, ab.w * inv);
    }
}

// ---------------------------------------------------------------------------
extern "C" void kernel_launch(void* const* d_in, const int* in_sizes, int n_in,
                              void* d_out, int out_size, void* d_ws, size_t ws_size,
                              hipStream_t stream) {
    const float* x    = (const float*)d_in[0];
    const float* beta = (const float*)d_in[1];
    const int*   row  = (const int*)d_in[2];
    const int*   col  = (const int*)d_in[3];
    float*       out  = (float*)d_out;

    const int N = in_sizes[0] / FEAT;   // 50000
    const int E = in_sizes[2];          // 800000

    // Workspace layout (512B-aligned chunks):
    // rn[N] | nrm[N] | row_ptr[N+1] | zip[E] int2 | xhn[N*8 uint4]
    char*  ws = (char*)d_ws;
    size_t o  = 0;
    auto alloc = [&](size_t bytes) {
        size_t cur = o;
        o = (o + bytes + 511) & ~(size_t)511;
        return cur;
    };
    float* rn      = (float*)(ws + alloc((size_t)N * 4));
    float* nrm     = (float*)(ws + alloc((size_t)N * 4));
    int*   row_ptr = (int*)  (ws + alloc((size_t)(N + 1) * 4));
    int2*  zip     = (int2*) (ws + alloc((size_t)E * 8));
    uint4* xhn     = (uint4*)(ws + alloc((size_t)N * 128));

    {   // prep1: norms + normalized bf16 mirror + rowptr
        int normBlocks = (N + 31) / 32;
        int edgeBlocks = (E + 255) / 256;
        prep1_kernel<<<normBlocks + edgeBlocks, 256, 0, stream>>>(
            x, rn, nrm, xhn, row, row_ptr, N, E, normBlocks);
    }
    {   // prep2: zip col+nrm per edge
        int grid = (E + 255) / 256;
        prep2_kernel<<<grid, 256, 0, stream>>>(col, nrm, zip, E);
    }
    {   // fused: 8 rows per wave, 4 waves per block, depth-8 pipeline
        int waves = (N + 7) / 8;
        int grid  = (waves + 3) / 4;
        fused_kernel<<<grid, 256, 0, stream>>>(
            x, xhn, rn, beta, row_ptr, zip, out, N);
    }
}

// Round 13
// 40.410 us; speedup vs baseline: 6.2570x; 6.2570x over previous
//
#include <hip/hip_runtime.h>
#include <hip/hip_bf16.h>

#define FEAT 64

// RNE pack of two fp32 into one u32 of 2 bf16 (lo, hi)
__device__ inline uint packbf2(float lo, float hi) {
    uint ul = __float_as_uint(lo), uh = __float_as_uint(hi);
    ul += 0x7FFFu + ((ul >> 16) & 1u);
    uh += 0x7FFFu + ((uh >> 16) & 1u);
    return (ul >> 16) | (uh & 0xFFFF0000u);
}

// unpack uint4 (8 bf16) -> two float4
__device__ inline void unpack8(uint4 q, float4& va, float4& vb) {
    va.x = __uint_as_float(q.x << 16);
    va.y = __uint_as_float(q.x & 0xFFFF0000u);
    va.z = __uint_as_float(q.y << 16);
    va.w = __uint_as_float(q.y & 0xFFFF0000u);
    vb.x = __uint_as_float(q.z << 16);
    vb.y = __uint_as_float(q.z & 0xFFFF0000u);
    vb.z = __uint_as_float(q.w << 16);
    vb.w = __uint_as_float(q.w & 0xFFFF0000u);
}

// ---------------------------------------------------------------------------
// prep1: blocks [0,normBlocks): inverse norms rn, raw norms nrm, and the
// NORMALIZED bf16 mirror xhn = bf16(x * rn) (feature-permuted: lane sub
// holds feats [4s,4s+4) and [32+4s,..) in one uint4).  Remaining blocks:
// row_ptr build from the SORTED row_index.
// ---------------------------------------------------------------------------
__global__ void prep1_kernel(const float* __restrict__ x,
                             float* __restrict__ rn,
                             float* __restrict__ nrm,
                             uint4* __restrict__ xhn,
                             const int* __restrict__ row,
                             int* __restrict__ row_ptr,
                             int N, int E, int normBlocks) {
    if ((int)blockIdx.x < normBlocks) {
        int wid  = blockIdx.x * (blockDim.x >> 6) + (threadIdx.x >> 6);
        int lane = threadIdx.x & 63;
        int g    = lane >> 3;
        int sub  = lane & 7;
        int r    = wid * 8 + g;
        if (r >= N) return;
        const char* xB = (const char*)x;
        uint roff = ((uint)r << 8) + ((uint)sub << 4);
        float4 xa = *reinterpret_cast<const float4*>(xB + roff);
        float4 xb = *reinterpret_cast<const float4*>(xB + roff + 128);
        float q = xa.x*xa.x + xa.y*xa.y + xa.z*xa.z + xa.w*xa.w
                + xb.x*xb.x + xb.y*xb.y + xb.z*xb.z + xb.w*xb.w;
        q += __shfl_xor(q, 1);
        q += __shfl_xor(q, 2);
        q += __shfl_xor(q, 4);
        float qe  = q + 1e-8f;
        float rnr = rsqrtf(qe);
        if (sub == 0) { rn[r] = rnr; nrm[r] = qe * rnr; }   // nrm = sqrt(qe)
        uint4 p;
        p.x = packbf2(xa.x * rnr, xa.y * rnr);
        p.y = packbf2(xa.z * rnr, xa.w * rnr);
        p.z = packbf2(xb.x * rnr, xb.y * rnr);
        p.w = packbf2(xb.z * rnr, xb.w * rnr);
        xhn[r * 8 + sub] = p;
    } else {
        int e = (blockIdx.x - normBlocks) * blockDim.x + threadIdx.x;
        if (e >= E) return;
        int curr = row[e];
        if (e == 0) {
            for (int r = 0; r <= curr; ++r) row_ptr[r] = 0;
        } else {
            int prev = row[e - 1];
            for (int r = prev + 1; r <= curr; ++r) row_ptr[r] = e;
        }
        if (e == E - 1) {
            for (int r = curr + 1; r <= N; ++r) row_ptr[r] = E;
        }
    }
}

// ---------------------------------------------------------------------------
// prep2: zip[e] = { col[e], bits(nrm[col[e]]) }.  Moves the scattered 4B
// norm probes out of the fused hot loop into a max-MLP edge-parallel pass.
// ---------------------------------------------------------------------------
__global__ void prep2_kernel(const int* __restrict__ col,
                             const float* __restrict__ nrm,
                             int2* __restrict__ zip, int E) {
    int e = blockIdx.x * blockDim.x + threadIdx.x;
    if (e >= E) return;
    int c = col[e];
    zip[e] = make_int2(c, __float_as_int(nrm[c]));
}

// ---------------------------------------------------------------------------
// FUSED attention + shift-free softmax + aggregation (round-8 structure).
// 8 rows per wave (one 8-lane group per row).  Per 8-edge chunk: one
// coalesced 8B zip load per lane; quads of 4 edges processed with the next
// quad's 4 gathers already in flight (depth-4 pipeline, no spills).
// Gathers are UNGUARDED (zip zero-init -> row 0 dummy, masked by e=0).
// ---------------------------------------------------------------------------
__global__ void fused_kernel(const float* __restrict__ x,
                             const uint4* __restrict__ xhn,
                             const float* __restrict__ rn,
                             const float* __restrict__ beta,
                             const int* __restrict__ row_ptr,
                             const int2* __restrict__ zip,
                             float* __restrict__ out, int N) {
    int wid  = blockIdx.x * (blockDim.x >> 6) + (threadIdx.x >> 6);
    int lane = threadIdx.x & 63;
    int g    = lane >> 3;               // group = row slot (0..7)
    int sub  = lane & 7;
    int r    = wid * 8 + g;
    bool rv  = (r < N);

    int start = 0, deg = 0;
    if (rv) {
        start = row_ptr[r];
        deg   = row_ptr[r + 1] - start;
    }

    // x_r scaled by beta*rn_r:  att = dot(xr_scaled, xhn_c)
    float4 xa = make_float4(0.f, 0.f, 0.f, 0.f);
    float4 xb = make_float4(0.f, 0.f, 0.f, 0.f);
    if (rv) {
        const char* xB = (const char*)x;
        uint roff = ((uint)r << 8) + ((uint)sub << 4);
        xa = *reinterpret_cast<const float4*>(xB + roff);
        xb = *reinterpret_cast<const float4*>(xB + roff + 128);
        float brn = beta[0] * rn[r];
        xa.x *= brn; xa.y *= brn; xa.z *= brn; xa.w *= brn;
        xb.x *= brn; xb.y *= brn; xb.z *= brn; xb.w *= brn;
    }

    // zip chunks: A = edges [a, a+8), B = [a+8, a+16)   (zero-init = safe)
    int2 zipA = make_int2(0, 0), zipB = make_int2(0, 0);
    if (sub < deg)     zipA = zip[start + sub];
    if (8 + sub < deg) zipB = zip[start + 8 + sub];

    // prologue: fetch quad 0 (chunk A, kk 0..3), unguarded
    int   c0 = __shfl(zipA.x, 0, 8), c1 = __shfl(zipA.x, 1, 8);
    int   c2 = __shfl(zipA.x, 2, 8), c3 = __shfl(zipA.x, 3, 8);
    float n0 = __shfl(__int_as_float(zipA.y), 0, 8);
    float n1 = __shfl(__int_as_float(zipA.y), 1, 8);
    float n2 = __shfl(__int_as_float(zipA.y), 2, 8);
    float n3 = __shfl(__int_as_float(zipA.y), 3, 8);
    uint4 q0 = xhn[(uint)c0 * 8u + sub], q1 = xhn[(uint)c1 * 8u + sub];
    uint4 q2 = xhn[(uint)c2 * 8u + sub], q3 = xhn[(uint)c3 * 8u + sub];

    float  s  = 0.f;
    float4 aa = make_float4(0.f, 0.f, 0.f, 0.f);
    float4 ab = make_float4(0.f, 0.f, 0.f, 0.f);

    for (int base = 0; base < deg; base += 4) {
        // rotate chunks at 8-boundaries; refill B
        if (base && (base & 7) == 0) {
            zipA = zipB;
            zipB = make_int2(0, 0);
            if (base + 8 + sub < deg) zipB = zip[start + base + 8 + sub];
        }
        // issue gathers for next quad (edges base+4..base+7), unguarded
        int  nkk = (base + 4) & 7;               // 4 -> chunk A, 0 -> chunk B
        int2 cS  = (nkk == 4) ? zipA : zipB;
        int   nc0 = __shfl(cS.x, nkk + 0, 8), nc1 = __shfl(cS.x, nkk + 1, 8);
        int   nc2 = __shfl(cS.x, nkk + 2, 8), nc3 = __shfl(cS.x, nkk + 3, 8);
        float nn0 = __shfl(__int_as_float(cS.y), nkk + 0, 8);
        float nn1 = __shfl(__int_as_float(cS.y), nkk + 1, 8);
        float nn2 = __shfl(__int_as_float(cS.y), nkk + 2, 8);
        float nn3 = __shfl(__int_as_float(cS.y), nkk + 3, 8);
        uint4 nq0 = xhn[(uint)nc0 * 8u + sub], nq1 = xhn[(uint)nc1 * 8u + sub];
        uint4 nq2 = xhn[(uint)nc2 * 8u + sub], nq3 = xhn[(uint)nc3 * 8u + sub];

        // process current quad
        float4 va0, vb0, va1, vb1, va2, vb2, va3, vb3;
        unpack8(q0, va0, vb0);  unpack8(q1, va1, vb1);
        unpack8(q2, va2, vb2);  unpack8(q3, va3, vb3);

        float d0 = xa.x*va0.x + xa.y*va0.y + xa.z*va0.z + xa.w*va0.w
                 + xb.x*vb0.x + xb.y*vb0.y + xb.z*vb0.z + xb.w*vb0.w;
        float d1 = xa.x*va1.x + xa.y*va1.y + xa.z*va1.z + xa.w*va1.w
                 + xb.x*vb1.x + xb.y*vb1.y + xb.z*vb1.z + xb.w*vb1.w;
        float d2 = xa.x*va2.x + xa.y*va2.y + xa.z*va2.z + xa.w*va2.w
                 + xb.x*vb2.x + xb.y*vb2.y + xb.z*vb2.z + xb.w*vb2.w;
        float d3 = xa.x*va3.x + xa.y*va3.y + xa.z*va3.z + xa.w*va3.w
                 + xb.x*vb3.x + xb.y*vb3.y + xb.z*vb3.z + xb.w*vb3.w;
        d0 += __shfl_xor(d0, 1);  d1 += __shfl_xor(d1, 1);
        d2 += __shfl_xor(d2, 1);  d3 += __shfl_xor(d3, 1);
        d0 += __shfl_xor(d0, 2);  d1 += __shfl_xor(d1, 2);
        d2 += __shfl_xor(d2, 2);  d3 += __shfl_xor(d3, 2);
        d0 += __shfl_xor(d0, 4);  d1 += __shfl_xor(d1, 4);
        d2 += __shfl_xor(d2, 4);  d3 += __shfl_xor(d3, 4);

        float e0 = (base + 0 < deg) ? __expf(d0) : 0.f;  // att bounded by |beta|
        float e1 = (base + 1 < deg) ? __expf(d1) : 0.f;
        float e2 = (base + 2 < deg) ? __expf(d2) : 0.f;
        float e3 = (base + 3 < deg) ? __expf(d3) : 0.f;
        s += (e0 + e1) + (e2 + e3);

        float w0 = e0 * n0, w1 = e1 * n1, w2 = e2 * n2, w3 = e3 * n3;
        aa.x += w0*va0.x + w1*va1.x + w2*va2.x + w3*va3.x;
        aa.y += w0*va0.y + w1*va1.y + w2*va2.y + w3*va3.y;
        aa.z += w0*va0.z + w1*va1.z + w2*va2.z + w3*va3.z;
        aa.w += w0*va0.w + w1*va1.w + w2*va2.w + w3*va3.w;
        ab.x += w0*vb0.x + w1*vb1.x + w2*vb2.x + w3*vb3.x;
        ab.y += w0*vb0.y + w1*vb1.y + w2*vb2.y + w3*vb3.y;
        ab.z += w0*vb0.z + w1*vb1.z + w2*vb2.z + w3*vb3.z;
        ab.w += w0*vb0.w + w1*vb1.w + w2*vb2.w + w3*vb3.w;

        // rotate pipeline
        q0 = nq0; q1 = nq1; q2 = nq2; q3 = nq3;
        n0 = nn0; n1 = nn1; n2 = nn2; n3 = nn3;
    }

    float inv = 1.0f / fmaxf(s, 1e-16f);      // deg==0 -> out = 0
    if (rv) {
        uint roff = ((uint)r << 8) + ((uint)sub << 4);
        *reinterpret_cast<float4*>((char*)out + roff) =
            make_float4(aa.x * inv, aa.y * inv, aa.z * inv, aa.w * inv);
        *reinterpret_cast<float4*>((char*)out + roff + 128) =
            make_float4(ab.x * inv, ab.y * inv, ab.z * inv, ab.w * inv);
    }
}

// ---------------------------------------------------------------------------
extern "C" void kernel_launch(void* const* d_in, const int* in_sizes, int n_in,
                              void* d_out, int out_size, void* d_ws, size_t ws_size,
                              hipStream_t stream) {
    const float* x    = (const float*)d_in[0];
    const float* beta = (const float*)d_in[1];
    const int*   row  = (const int*)d_in[2];
    const int*   col  = (const int*)d_in[3];
    float*       out  = (float*)d_out;

    const int N = in_sizes[0] / FEAT;   // 50000
    const int E = in_sizes[2];          // 800000

    // Workspace layout (512B-aligned chunks):
    // rn[N] | nrm[N] | row_ptr[N+1] | zip[E] int2 | xhn[N*8 uint4]
    char*  ws = (char*)d_ws;
    size_t o  = 0;
    auto alloc = [&](size_t bytes) {
        size_t cur = o;
        o = (o + bytes + 511) & ~(size_t)511;
        return cur;
    };
    float* rn      = (float*)(ws + alloc((size_t)N * 4));
    float* nrm     = (float*)(ws + alloc((size_t)N * 4));
    int*   row_ptr = (int*)  (ws + alloc((size_t)(N + 1) * 4));
    int2*  zip     = (int2*) (ws + alloc((size_t)E * 8));
    uint4* xhn     = (uint4*)(ws + alloc((size_t)N * 128));

    {   // prep1: norms + normalized bf16 mirror + rowptr
        int normBlocks = (N + 31) / 32;
        int edgeBlocks = (E + 255) / 256;
        prep1_kernel<<<normBlocks + edgeBlocks, 256, 0, stream>>>(
            x, rn, nrm, xhn, row, row_ptr, N, E, normBlocks);
    }
    {   // prep2: zip col+nrm per edge
        int grid = (E + 255) / 256;
        prep2_kernel<<<grid, 256, 0, stream>>>(col, nrm, zip, E);
    }
    {   // fused: 8 rows per wave, 4 waves per block, depth-4 pipeline
        int waves = (N + 7) / 8;
        int grid  = (waves + 3) / 4;
        fused_kernel<<<grid, 256, 0, stream>>>(
            x, xhn, rn, beta, row_ptr, zip, out, N);
    }
}

// Round 14
// 38.528 us; speedup vs baseline: 6.5627x; 1.0488x over previous
//
#include <hip/hip_runtime.h>
#include <hip/hip_fp16.h>

#define FEAT 64

typedef _Float16 h2 __attribute__((ext_vector_type(2)));
union HU { uint u; h2 h; };
__device__ inline h2   u2h(uint u) { HU x; x.u = u; return x.h; }
__device__ inline uint h2u(h2 h)   { HU x; x.h = h; return x.u; }
__device__ inline uint packh2f(float lo, float hi) {
    h2 v; v[0] = (_Float16)lo; v[1] = (_Float16)hi; return h2u(v);
}

// 8-feature dot: q holds 8 fp16 (4 x half2), x0..x3 the matching row pairs.
__device__ inline float dot8(uint4 q, h2 x0, h2 x1, h2 x2, h2 x3) {
#if __has_builtin(__builtin_amdgcn_fdot2)
    float d = __builtin_amdgcn_fdot2(u2h(q.x), x0, 0.f, false);
    d = __builtin_amdgcn_fdot2(u2h(q.y), x1, d, false);
    d = __builtin_amdgcn_fdot2(u2h(q.z), x2, d, false);
    d = __builtin_amdgcn_fdot2(u2h(q.w), x3, d, false);
    return d;
#else
    h2 a = u2h(q.x), b = u2h(q.y), c = u2h(q.z), e = u2h(q.w);
    return (float)a[0]*(float)x0[0] + (float)a[1]*(float)x0[1]
         + (float)b[0]*(float)x1[0] + (float)b[1]*(float)x1[1]
         + (float)c[0]*(float)x2[0] + (float)c[1]*(float)x2[1]
         + (float)e[0]*(float)x3[0] + (float)e[1]*(float)x3[1];
#endif
}

// ---------------------------------------------------------------------------
// prep1: blocks [0,normBlocks): inverse norms rn, raw norms nrm, and the
// NORMALIZED fp16 mirror xhn = fp16(x * rn) (feature-permuted: lane sub
// holds feats [4s,4s+4) and [32+4s,..) in one uint4 = 8 fp16).  Remaining
// blocks: row_ptr build from the SORTED row_index.
// ---------------------------------------------------------------------------
__global__ void prep1_kernel(const float* __restrict__ x,
                             float* __restrict__ rn,
                             float* __restrict__ nrm,
                             uint4* __restrict__ xhn,
                             const int* __restrict__ row,
                             int* __restrict__ row_ptr,
                             int N, int E, int normBlocks) {
    if ((int)blockIdx.x < normBlocks) {
        int wid  = blockIdx.x * (blockDim.x >> 6) + (threadIdx.x >> 6);
        int lane = threadIdx.x & 63;
        int g    = lane >> 3;
        int sub  = lane & 7;
        int r    = wid * 8 + g;
        if (r >= N) return;
        const char* xB = (const char*)x;
        uint roff = ((uint)r << 8) + ((uint)sub << 4);
        float4 xa = *reinterpret_cast<const float4*>(xB + roff);
        float4 xb = *reinterpret_cast<const float4*>(xB + roff + 128);
        float q = xa.x*xa.x + xa.y*xa.y + xa.z*xa.z + xa.w*xa.w
                + xb.x*xb.x + xb.y*xb.y + xb.z*xb.z + xb.w*xb.w;
        q += __shfl_xor(q, 1);
        q += __shfl_xor(q, 2);
        q += __shfl_xor(q, 4);
        float qe  = q + 1e-8f;
        float rnr = rsqrtf(qe);
        if (sub == 0) { rn[r] = rnr; nrm[r] = qe * rnr; }   // nrm = sqrt(qe)
        uint4 p;
        p.x = packh2f(xa.x * rnr, xa.y * rnr);
        p.y = packh2f(xa.z * rnr, xa.w * rnr);
        p.z = packh2f(xb.x * rnr, xb.y * rnr);
        p.w = packh2f(xb.z * rnr, xb.w * rnr);
        xhn[r * 8 + sub] = p;
    } else {
        int e = (blockIdx.x - normBlocks) * blockDim.x + threadIdx.x;
        if (e >= E) return;
        int curr = row[e];
        if (e == 0) {
            for (int r = 0; r <= curr; ++r) row_ptr[r] = 0;
        } else {
            int prev = row[e - 1];
            for (int r = prev + 1; r <= curr; ++r) row_ptr[r] = e;
        }
        if (e == E - 1) {
            for (int r = curr + 1; r <= N; ++r) row_ptr[r] = E;
        }
    }
}

// ---------------------------------------------------------------------------
// prep2: zip[e] = { col[e], bits(nrm[col[e]]) }.
// ---------------------------------------------------------------------------
__global__ void prep2_kernel(const int* __restrict__ col,
                             const float* __restrict__ nrm,
                             int2* __restrict__ zip, int E) {
    int e = blockIdx.x * blockDim.x + threadIdx.x;
    if (e >= E) return;
    int c = col[e];
    zip[e] = make_int2(c, __float_as_int(nrm[c]));
}

// ---------------------------------------------------------------------------
// FUSED attention + shift-free softmax + aggregation, fp16 inner math.
// 8 rows per wave (8-lane group per row), depth-4 gather pipeline.
// Per edge: 4 v_dot2_f32_f16 (no unpack), 3-shfl reduce, exp, w-cvt,
// 4 v_pk_fma_f16 into per-quad half2 partials, folded to fp32 per quad.
// ---------------------------------------------------------------------------
__global__ void fused_kernel(const float* __restrict__ x,
                             const uint4* __restrict__ xhn,
                             const float* __restrict__ rn,
                             const float* __restrict__ beta,
                             const int* __restrict__ row_ptr,
                             const int2* __restrict__ zip,
                             float* __restrict__ out, int N) {
    int wid  = blockIdx.x * (blockDim.x >> 6) + (threadIdx.x >> 6);
    int lane = threadIdx.x & 63;
    int g    = lane >> 3;               // group = row slot (0..7)
    int sub  = lane & 7;
    int r    = wid * 8 + g;
    bool rv  = (r < N);

    int start = 0, deg = 0;
    if (rv) {
        start = row_ptr[r];
        deg   = row_ptr[r + 1] - start;
    }

    // x_r scaled by beta*rn_r, converted to 4 half2 pairs
    h2 xr0, xr1, xr2, xr3;
    {
        float4 xa = make_float4(0.f, 0.f, 0.f, 0.f);
        float4 xb = make_float4(0.f, 0.f, 0.f, 0.f);
        if (rv) {
            const char* xB = (const char*)x;
            uint roff = ((uint)r << 8) + ((uint)sub << 4);
            xa = *reinterpret_cast<const float4*>(xB + roff);
            xb = *reinterpret_cast<const float4*>(xB + roff + 128);
            float brn = beta[0] * rn[r];
            xa.x *= brn; xa.y *= brn; xa.z *= brn; xa.w *= brn;
            xb.x *= brn; xb.y *= brn; xb.z *= brn; xb.w *= brn;
        }
        xr0 = u2h(packh2f(xa.x, xa.y));
        xr1 = u2h(packh2f(xa.z, xa.w));
        xr2 = u2h(packh2f(xb.x, xb.y));
        xr3 = u2h(packh2f(xb.z, xb.w));
    }

    // zip chunks: A = edges [a, a+8), B = [a+8, a+16)   (zero-init = safe)
    int2 zipA = make_int2(0, 0), zipB = make_int2(0, 0);
    if (sub < deg)     zipA = zip[start + sub];
    if (8 + sub < deg) zipB = zip[start + 8 + sub];

    // prologue: fetch quad 0 (chunk A, kk 0..3), unguarded
    int   c0 = __shfl(zipA.x, 0, 8), c1 = __shfl(zipA.x, 1, 8);
    int   c2 = __shfl(zipA.x, 2, 8), c3 = __shfl(zipA.x, 3, 8);
    float n0 = __shfl(__int_as_float(zipA.y), 0, 8);
    float n1 = __shfl(__int_as_float(zipA.y), 1, 8);
    float n2 = __shfl(__int_as_float(zipA.y), 2, 8);
    float n3 = __shfl(__int_as_float(zipA.y), 3, 8);
    uint4 q0 = xhn[(uint)c0 * 8u + sub], q1 = xhn[(uint)c1 * 8u + sub];
    uint4 q2 = xhn[(uint)c2 * 8u + sub], q3 = xhn[(uint)c3 * 8u + sub];

    float  s  = 0.f;
    float4 aa = make_float4(0.f, 0.f, 0.f, 0.f);
    float4 ab = make_float4(0.f, 0.f, 0.f, 0.f);

    for (int base = 0; base < deg; base += 4) {
        // rotate chunks at 8-boundaries; refill B
        if (base && (base & 7) == 0) {
            zipA = zipB;
            zipB = make_int2(0, 0);
            if (base + 8 + sub < deg) zipB = zip[start + base + 8 + sub];
        }
        // issue gathers for next quad (edges base+4..base+7), unguarded
        int  nkk = (base + 4) & 7;               // 4 -> chunk A, 0 -> chunk B
        int2 cS  = (nkk == 4) ? zipA : zipB;
        int   nc0 = __shfl(cS.x, nkk + 0, 8), nc1 = __shfl(cS.x, nkk + 1, 8);
        int   nc2 = __shfl(cS.x, nkk + 2, 8), nc3 = __shfl(cS.x, nkk + 3, 8);
        float nn0 = __shfl(__int_as_float(cS.y), nkk + 0, 8);
        float nn1 = __shfl(__int_as_float(cS.y), nkk + 1, 8);
        float nn2 = __shfl(__int_as_float(cS.y), nkk + 2, 8);
        float nn3 = __shfl(__int_as_float(cS.y), nkk + 3, 8);
        uint4 nq0 = xhn[(uint)nc0 * 8u + sub], nq1 = xhn[(uint)nc1 * 8u + sub];
        uint4 nq2 = xhn[(uint)nc2 * 8u + sub], nq3 = xhn[(uint)nc3 * 8u + sub];

        // ---- dots (fp16 hw dot, fp32 accumulate) ----
        float d0 = dot8(q0, xr0, xr1, xr2, xr3);
        float d1 = dot8(q1, xr0, xr1, xr2, xr3);
        float d2 = dot8(q2, xr0, xr1, xr2, xr3);
        float d3 = dot8(q3, xr0, xr1, xr2, xr3);
        d0 += __shfl_xor(d0, 1);  d1 += __shfl_xor(d1, 1);
        d2 += __shfl_xor(d2, 1);  d3 += __shfl_xor(d3, 1);
        d0 += __shfl_xor(d0, 2);  d1 += __shfl_xor(d1, 2);
        d2 += __shfl_xor(d2, 2);  d3 += __shfl_xor(d3, 2);
        d0 += __shfl_xor(d0, 4);  d1 += __shfl_xor(d1, 4);
        d2 += __shfl_xor(d2, 4);  d3 += __shfl_xor(d3, 4);

        float e0 = (base + 0 < deg) ? __expf(d0) : 0.f;  // att bounded by |beta|
        float e1 = (base + 1 < deg) ? __expf(d1) : 0.f;
        float e2 = (base + 2 < deg) ? __expf(d2) : 0.f;
        float e3 = (base + 3 < deg) ? __expf(d3) : 0.f;
        s += (e0 + e1) + (e2 + e3);

        // ---- packed fp16 aggregation, per-quad partials ----
        float w0 = e0 * n0, w1 = e1 * n1, w2 = e2 * n2, w3 = e3 * n3;
        h2 wh0; wh0[0] = (_Float16)w0; wh0[1] = wh0[0];
        h2 wh1; wh1[0] = (_Float16)w1; wh1[1] = wh1[0];
        h2 wh2; wh2[0] = (_Float16)w2; wh2[1] = wh2[0];
        h2 wh3; wh3[0] = (_Float16)w3; wh3[1] = wh3[0];

        h2 p0 = u2h(q0.x) * wh0;  p0 = u2h(q1.x) * wh1 + p0;
        p0 = u2h(q2.x) * wh2 + p0;  p0 = u2h(q3.x) * wh3 + p0;
        h2 p1 = u2h(q0.y) * wh0;  p1 = u2h(q1.y) * wh1 + p1;
        p1 = u2h(q2.y) * wh2 + p1;  p1 = u2h(q3.y) * wh3 + p1;
        h2 p2 = u2h(q0.z) * wh0;  p2 = u2h(q1.z) * wh1 + p2;
        p2 = u2h(q2.z) * wh2 + p2;  p2 = u2h(q3.z) * wh3 + p2;
        h2 p3 = u2h(q0.w) * wh0;  p3 = u2h(q1.w) * wh1 + p3;
        p3 = u2h(q2.w) * wh2 + p3;  p3 = u2h(q3.w) * wh3 + p3;

        // fold quad partials into fp32 master accumulators
        aa.x += (float)p0[0];  aa.y += (float)p0[1];
        aa.z += (float)p1[0];  aa.w += (float)p1[1];
        ab.x += (float)p2[0];  ab.y += (float)p2[1];
        ab.z += (float)p3[0];  ab.w += (float)p3[1];

        // rotate pipeline
        q0 = nq0; q1 = nq1; q2 = nq2; q3 = nq3;
        n0 = nn0; n1 = nn1; n2 = nn2; n3 = nn3;
    }

    float inv = 1.0f / fmaxf(s, 1e-16f);      // deg==0 -> out = 0
    if (rv) {
        uint roff = ((uint)r << 8) + ((uint)sub << 4);
        *reinterpret_cast<float4*>((char*)out + roff) =
            make_float4(aa.x * inv, aa.y * inv, aa.z * inv, aa.w * inv);
        *reinterpret_cast<float4*>((char*)out + roff + 128) =
            make_float4(ab.x * inv, ab.y * inv, ab.z * inv, ab.w * inv);
    }
}

// ---------------------------------------------------------------------------
extern "C" void kernel_launch(void* const* d_in, const int* in_sizes, int n_in,
                              void* d_out, int out_size, void* d_ws, size_t ws_size,
                              hipStream_t stream) {
    const float* x    = (const float*)d_in[0];
    const float* beta = (const float*)d_in[1];
    const int*   row  = (const int*)d_in[2];
    const int*   col  = (const int*)d_in[3];
    float*       out  = (float*)d_out;

    const int N = in_sizes[0] / FEAT;   // 50000
    const int E = in_sizes[2];          // 800000

    // Workspace layout (512B-aligned chunks):
    // rn[N] | nrm[N] | row_ptr[N+1] | zip[E] int2 | xhn[N*8 uint4]
    char*  ws = (char*)d_ws;
    size_t o  = 0;
    auto alloc = [&](size_t bytes) {
        size_t cur = o;
        o = (o + bytes + 511) & ~(size_t)511;
        return cur;
    };
    float* rn      = (float*)(ws + alloc((size_t)N * 4));
    float* nrm     = (float*)(ws + alloc((size_t)N * 4));
    int*   row_ptr = (int*)  (ws + alloc((size_t)(N + 1) * 4));
    int2*  zip     = (int2*) (ws + alloc((size_t)E * 8));
    uint4* xhn     = (uint4*)(ws + alloc((size_t)N * 128));

    {   // prep1: norms + normalized fp16 mirror + rowptr
        int normBlocks = (N + 31) / 32;
        int edgeBlocks = (E + 255) / 256;
        prep1_kernel<<<normBlocks + edgeBlocks, 256, 0, stream>>>(
            x, rn, nrm, xhn, row, row_ptr, N, E, normBlocks);
    }
    {   // prep2: zip col+nrm per edge
        int grid = (E + 255) / 256;
        prep2_kernel<<<grid, 256, 0, stream>>>(col, nrm, zip, E);
    }
    {   // fused: 8 rows per wave, 4 waves per block, depth-4 pipeline
        int waves = (N + 7) / 8;
        int grid  = (waves + 3) / 4;
        fused_kernel<<<grid, 256, 0, stream>>>(
            x, xhn, rn, beta, row_ptr, zip, out, N);
    }
}